// Round 9
// baseline (602.974 us; speedup 1.0000x reference)
//
#include <hip/hip_runtime.h>
#include <hip/hip_cooperative_groups.h>

namespace cg = cooperative_groups;

// ProbOhemCrossEntropy2d on MI355X — round 9: single cooperative kernel.
// pred [8,19,768,768] f32, target [8,768,768] i32 -> scalar f32 loss.
//
// Fast path (threshold==0.7, decided from hist1 alone):
//   zero -> sync -> pass1(softmax+hist+spec/tot accum) -> sync -> out. 1 dispatch.
// Slow path (exact 3-level radix select) stays in-kernel, uniform branch.
// Fallback: proven 6-dispatch pipeline if cooperative launch unavailable.

#define CC 19
#define HWSZ 589824            // 768*768
#define NPIX 4718592           // 8*HWSZ
#define NQUAD (NPIX / 4)       // 1179648
#define KSEL 262144
#define IGNORE_LBL 255
#define THR 0.7f
#define NBLK 1152              // fallback-path grid
#define ITERS 4                // fallback: NQUAD / (NBLK*256) == 4 exactly
#define BIN_07 505             // 0x3F333333 >> 21

// ws layout (u32 words):
// [1] spec_cnt  [2] tot_cnt (== num_valid)  [3] slow_cnt  [4] early_flag
// [6..7] slow_sum (double)  [8..9] spec_sum (double)  [10..11] tot_sum (double)
// [16..+2048) hist1  [..+2048) hist2  [..+1024) hist3
// [8192..+NPIX) prob bits
#define W_SPEC_CNT 1
#define W_TOT_CNT 2
#define W_SLOW_CNT 3
#define W_EARLY 4
#define W_SLOW_SUM 6
#define W_SPEC_SUM 8
#define W_TOT_SUM 10
#define HIST1_OFF 16
#define HIST2_OFF (HIST1_OFF + 2048)
#define HIST3_OFF (HIST2_OFF + 2048)
#define META_WORDS 8192
#define PROB_OFF META_WORDS

// ---------- shared device helpers ----------

// True iff threshold is exactly 0.7f (conservative: counts hist1 bins
// [0,505), i.e. prob < 0.625). Pure function of hist1 -> same answer in
// every block. All 256 threads must participate.
__device__ __forceinline__ bool early_thr(const unsigned* __restrict__ gh) {
    unsigned v = 0;
    for (int i = threadIdx.x; i < BIN_07; i += 256) v += gh[i];
    for (int off = 32; off; off >>= 1) v += __shfl_down(v, off);
    __shared__ unsigned cw[4];
    if ((threadIdx.x & 63) == 0) cw[threadIdx.x >> 6] = v;
    __syncthreads();
    unsigned c_lo = cw[0] + cw[1] + cw[2] + cw[3];
    __syncthreads();
    return c_lo >= (unsigned)KSEL;
}

// Block-local radix-select step (pure function of (gh, krem_in)).
template <int NBINS>
__device__ __forceinline__ void find_bin(const unsigned* __restrict__ gh,
                                         unsigned krem_in, int shift,
                                         unsigned& sel_io, unsigned& krem_out) {
    constexpr int CHUNK = NBINS / 256;
    __shared__ unsigned csum[256];
    __shared__ unsigned sb[2];
    const int t = threadIdx.x;
    __syncthreads();
    unsigned loc[CHUNK];
    unsigned s = 0;
#pragma unroll
    for (int j = 0; j < CHUNK; ++j) { loc[j] = gh[t * CHUNK + j]; s += loc[j]; }
    csum[t] = s;
    for (int off = 1; off < 256; off <<= 1) {
        __syncthreads();
        unsigned add = (t >= off) ? csum[t - off] : 0u;
        __syncthreads();
        csum[t] += add;
    }
    unsigned incl = csum[t];
    unsigned excl = incl - s;
    if (excl < krem_in && krem_in <= incl) {   // exactly one owner thread
        unsigned run = excl;
        unsigned bin = 0;
        bool found = false;
#pragma unroll
        for (int j = 0; j < CHUNK; ++j) {
            unsigned nrun = run + loc[j];
            if (!found && nrun >= krem_in) { bin = (unsigned)(t * CHUNK + j); found = true; }
            if (!found) run = nrun;
        }
        sb[0] = bin;
        sb[1] = krem_in - run;
    }
    __syncthreads();
    sel_io |= sb[0] << shift;
    krem_out = sb[1];
}

// Per-quad softmax: computes prob bits + accumulates spec/tot.
__device__ __forceinline__ void do_quad(const float* __restrict__ pred,
                                        const int* __restrict__ target,
                                        unsigned* __restrict__ ws,
                                        unsigned* __restrict__ lhist,
                                        int q, float& ls_spec, float& ls_tot,
                                        unsigned& lc_spec, unsigned& lc_tot) {
    int pix0 = q * 4;
    int b = pix0 / HWSZ;
    int hw = pix0 - b * HWSZ;
    const float* base = pred + (size_t)b * ((size_t)CC * HWSZ) + hw;

    float x[CC][4];
#pragma unroll
    for (int c = 0; c < CC; ++c) {
        float4 v = *reinterpret_cast<const float4*>(base + (size_t)c * HWSZ);
        x[c][0] = v.x; x[c][1] = v.y; x[c][2] = v.z; x[c][3] = v.w;
    }
    int4 t4 = *reinterpret_cast<const int4*>(target + pix0);
    int tt[4] = {t4.x, t4.y, t4.z, t4.w};

    unsigned pb[4];
#pragma unroll
    for (int p = 0; p < 4; ++p) {
        int t = tt[p];
        bool valid = (t != IGNORE_LBL);
        int tc = valid ? t : 0;
        float m = x[0][p];
#pragma unroll
        for (int c = 1; c < CC; ++c) m = fmaxf(m, x[c][p]);
        float s = 0.0f;
        float xt = x[0][p];
#pragma unroll
        for (int c = 0; c < CC; ++c) {
            float v = x[c][p];
            s += expf(v - m);
            xt = (c == tc) ? v : xt;   // cndmask, no runtime-indexed array
        }
        float lp = xt - m - logf(s);
        float pr = valid ? expf(lp) : 1.0f;
        pb[p] = __float_as_uint(pr);
        atomicAdd(&lhist[pb[p] >> 21], 1u);
        if (valid) {
            ls_tot += -lp; lc_tot += 1u;
            if (pr <= THR) { ls_spec += -lp; lc_spec += 1u; }
        }
    }
    *reinterpret_cast<uint4*>(ws + PROB_OFF + pix0) =
        make_uint4(pb[0], pb[1], pb[2], pb[3]);
}

// Block-reduce + global-atomic the four accumulators; then flush LDS hist.
__device__ __forceinline__ void flush_pass1(unsigned* __restrict__ ws,
                                            unsigned* __restrict__ lhist,
                                            float ls_spec, float ls_tot,
                                            unsigned lc_spec, unsigned lc_tot) {
    for (int off = 32; off; off >>= 1) {
        ls_spec += __shfl_down(ls_spec, off);
        ls_tot  += __shfl_down(ls_tot, off);
        lc_spec += __shfl_down(lc_spec, off);
        lc_tot  += __shfl_down(lc_tot, off);
    }
    __shared__ float fs[2][4];
    __shared__ unsigned us[2][4];
    if ((threadIdx.x & 63) == 0) {
        int w = threadIdx.x >> 6;
        fs[0][w] = ls_spec; fs[1][w] = ls_tot;
        us[0][w] = lc_spec; us[1][w] = lc_tot;
    }
    __syncthreads();   // also orders the LDS-hist atomics before the flush
    if (threadIdx.x == 0) {
        atomicAdd(reinterpret_cast<double*>(ws + W_SPEC_SUM),
                  (double)(fs[0][0] + fs[0][1] + fs[0][2] + fs[0][3]));
        atomicAdd(reinterpret_cast<double*>(ws + W_TOT_SUM),
                  (double)(fs[1][0] + fs[1][1] + fs[1][2] + fs[1][3]));
        atomicAdd(ws + W_SPEC_CNT, us[0][0] + us[0][1] + us[0][2] + us[0][3]);
        atomicAdd(ws + W_TOT_CNT, us[1][0] + us[1][1] + us[1][2] + us[1][3]);
    }
    int rot = (blockIdx.x & 7) << 8;
    for (int i = threadIdx.x; i < 2048; i += 256) {
        int idx = (i + rot) & 2047;
        unsigned v = lhist[idx];
        if (v) atomicAdd(ws + HIST1_OFF + idx, v);
    }
}

// ---------- fused cooperative kernel ----------

__global__ __launch_bounds__(256, 4) void k_fused(const float* __restrict__ pred,
                                                  const int* __restrict__ target,
                                                  unsigned* __restrict__ ws,
                                                  float* __restrict__ out) {
    cg::grid_group grid = cg::this_grid();
    const int gthreads = (int)gridDim.x * 256;
    const int gtid = (int)blockIdx.x * 256 + threadIdx.x;

    // phase 0: zero meta
    for (int i = gtid; i < META_WORDS; i += gthreads) ws[i] = 0u;

    __shared__ unsigned hist[2048];
    for (int i = threadIdx.x; i < 2048; i += 256) hist[i] = 0u;
    grid.sync();   // meta zeroed (block-level sync implied for hist)

    // phase 1: softmax + hist1 + speculative accumulators
    float ls_spec = 0.0f, ls_tot = 0.0f;
    unsigned lc_spec = 0, lc_tot = 0;
    for (int q = gtid; q < NQUAD; q += gthreads)
        do_quad(pred, target, ws, hist, q, ls_spec, ls_tot, lc_spec, lc_tot);
    flush_pass1(ws, hist, ls_spec, ls_tot, lc_spec, lc_tot);
    grid.sync();   // hist1 + spec/tot complete

    // phase 2: uniform decision
    bool early = early_thr(ws + HIST1_OFF);
    unsigned tot_cnt = ws[W_TOT_CNT];
    bool do_ohem = (tot_cnt > 0u) && (tot_cnt >= (unsigned)KSEL);
    if (early || !do_ohem) {                 // uniform across the whole grid
        if (blockIdx.x == 0 && threadIdx.x == 0) {
            double s; unsigned c;
            if (!do_ohem) { s = *reinterpret_cast<const double*>(ws + W_TOT_SUM);  c = tot_cnt; }
            else          { s = *reinterpret_cast<const double*>(ws + W_SPEC_SUM); c = ws[W_SPEC_CNT]; }
            out[0] = (float)(s / (double)((c > 0u) ? c : 1u));
        }
        return;
    }

    // ---- slow path: exact 3-level radix select (uniform branch) ----
    const uint4* pbv = reinterpret_cast<const uint4*>(ws + PROB_OFF);
    unsigned sel = 0, krem = 0;

    // refine level 2
    for (int i = threadIdx.x; i < 2048; i += 256) hist[i] = 0u;
    find_bin<2048>(ws + HIST1_OFF, (unsigned)KSEL, 21, sel, krem);  // leading sync covers zero-fill
    for (int q = gtid; q < NQUAD; q += gthreads) {
        uint4 v = pbv[q];
        unsigned a[4] = {v.x, v.y, v.z, v.w};
#pragma unroll
        for (int p = 0; p < 4; ++p)
            if ((a[p] >> 21) == (sel >> 21))
                atomicAdd(&hist[(a[p] >> 10) & 2047u], 1u);
    }
    __syncthreads();
    {
        int rot = (blockIdx.x & 3) << 8;
        for (int i = threadIdx.x; i < 2048; i += 256) {
            int idx = (i + rot) & 2047;
            unsigned v = hist[idx];
            if (v) atomicAdd(ws + HIST2_OFF + idx, v);
        }
    }
    grid.sync();

    // refine level 3
    for (int i = threadIdx.x; i < 1024; i += 256) hist[i] = 0u;
    find_bin<2048>(ws + HIST2_OFF, krem, 10, sel, krem);
    for (int q = gtid; q < NQUAD; q += gthreads) {
        uint4 v = pbv[q];
        unsigned a[4] = {v.x, v.y, v.z, v.w};
#pragma unroll
        for (int p = 0; p < 4; ++p)
            if ((a[p] >> 10) == (sel >> 10))
                atomicAdd(&hist[a[p] & 1023u], 1u);
    }
    __syncthreads();
    {
        int rot = (blockIdx.x & 3) << 8;
        for (int i = threadIdx.x; i < 1024; i += 256) {
            int idx = (i + rot) & 1023;
            unsigned v = hist[idx];
            if (v) atomicAdd(ws + HIST3_OFF + idx, v);
        }
    }
    grid.sync();

    // exact kth -> threshold; masked loss scan
    find_bin<1024>(ws + HIST3_OFF, krem, 0, sel, krem);
    float thr = fmaxf(__uint_as_float(sel), THR);
    float ls = 0.0f;
    unsigned lc = 0;
    for (int q = gtid; q < NQUAD; q += gthreads) {
        int pix0 = q * 4;
        uint4 v = pbv[q];
        int4 t4 = *reinterpret_cast<const int4*>(target + pix0);
        unsigned a[4] = {v.x, v.y, v.z, v.w};
        int tt[4] = {t4.x, t4.y, t4.z, t4.w};
#pragma unroll
        for (int p = 0; p < 4; ++p) {
            bool valid = (tt[p] != IGNORE_LBL);
            float pr = __uint_as_float(a[p]);
            if (valid && pr <= thr) { ls += -logf(fmaxf(pr, 1e-37f)); lc += 1u; }
        }
    }
    for (int off = 32; off; off >>= 1) {
        ls += __shfl_down(ls, off);
        lc += __shfl_down(lc, off);
    }
    __shared__ float wsum[4];
    __shared__ unsigned wcnt[4];
    if ((threadIdx.x & 63) == 0) { wsum[threadIdx.x >> 6] = ls; wcnt[threadIdx.x >> 6] = lc; }
    __syncthreads();
    if (threadIdx.x == 0) {
        atomicAdd(reinterpret_cast<double*>(ws + W_SLOW_SUM),
                  (double)(wsum[0] + wsum[1] + wsum[2] + wsum[3]));
        atomicAdd(ws + W_SLOW_CNT, wcnt[0] + wcnt[1] + wcnt[2] + wcnt[3]);
    }
    grid.sync();

    if (blockIdx.x == 0 && threadIdx.x == 0) {
        double s = *reinterpret_cast<const double*>(ws + W_SLOW_SUM);
        unsigned c = ws[W_SLOW_CNT];
        out[0] = (float)(s / (double)((c > 0u) ? c : 1u));
    }
}

// ---------- fallback: proven 6-dispatch pipeline (round-5 kernels) ----------

__global__ __launch_bounds__(256) void k_init(unsigned* __restrict__ ws) {
    for (int i = threadIdx.x; i < META_WORDS; i += 256) ws[i] = 0u;
}

__global__ __launch_bounds__(256) void k_pass1(const float* __restrict__ pred,
                                               const int* __restrict__ target,
                                               unsigned* __restrict__ ws) {
    __shared__ unsigned hist[2048];
    for (int i = threadIdx.x; i < 2048; i += 256) hist[i] = 0u;
    __syncthreads();
    float ls_spec = 0.0f, ls_tot = 0.0f;
    unsigned lc_spec = 0, lc_tot = 0;
    for (int it = 0; it < ITERS; ++it) {
        int q = it * (NBLK * 256) + blockIdx.x * 256 + threadIdx.x;
        do_quad(pred, target, ws, hist, q, ls_spec, ls_tot, lc_spec, lc_tot);
    }
    flush_pass1(ws, hist, ls_spec, ls_tot, lc_spec, lc_tot);
}

template <int LEVEL>
__global__ __launch_bounds__(256) void k_refine(unsigned* __restrict__ ws) {
    if (early_thr(ws + HIST1_OFF)) return;
    constexpr int NB = (LEVEL == 2) ? 2048 : 1024;
    __shared__ unsigned hist[NB];
    for (int i = threadIdx.x; i < NB; i += 256) hist[i] = 0u;
    unsigned sel = 0, krem = 0;
    find_bin<2048>(ws + HIST1_OFF, (unsigned)KSEL, 21, sel, krem);
    if (LEVEL == 3) find_bin<2048>(ws + HIST2_OFF, krem, 10, sel, krem);
    const uint4* pbv = reinterpret_cast<const uint4*>(ws + PROB_OFF);
    for (int it = 0; it < ITERS; ++it) {
        int q = it * (NBLK * 256) + blockIdx.x * 256 + threadIdx.x;
        uint4 v = pbv[q];
        unsigned a[4] = {v.x, v.y, v.z, v.w};
#pragma unroll
        for (int p = 0; p < 4; ++p) {
            unsigned bits = a[p];
            if (LEVEL == 2) {
                if ((bits >> 21) == (sel >> 21)) atomicAdd(&hist[(bits >> 10) & 2047u], 1u);
            } else {
                if ((bits >> 10) == (sel >> 10)) atomicAdd(&hist[bits & 1023u], 1u);
            }
        }
    }
    __syncthreads();
    unsigned* gh = ws + ((LEVEL == 2) ? HIST2_OFF : HIST3_OFF);
    int rot = (blockIdx.x & 3) << 8;
    for (int i = threadIdx.x; i < NB; i += 256) {
        int idx = (i + rot) & (NB - 1);
        unsigned v = hist[idx];
        if (v) atomicAdd(gh + idx, v);
    }
}

__global__ __launch_bounds__(256) void k_final(unsigned* __restrict__ ws,
                                               const int* __restrict__ target) {
    bool early = early_thr(ws + HIST1_OFF);
    unsigned tot_cnt = ws[W_TOT_CNT];
    bool do_ohem = (tot_cnt > 0u) && (tot_cnt >= (unsigned)KSEL);
    if (blockIdx.x == 0 && threadIdx.x == 0) ws[W_EARLY] = early ? 1u : 0u;
    if (early || !do_ohem) return;
    unsigned sel = 0, krem = 0;
    find_bin<2048>(ws + HIST1_OFF, (unsigned)KSEL, 21, sel, krem);
    find_bin<2048>(ws + HIST2_OFF, krem, 10, sel, krem);
    find_bin<1024>(ws + HIST3_OFF, krem, 0, sel, krem);
    float thr = fmaxf(__uint_as_float(sel), THR);
    const uint4* pbv = reinterpret_cast<const uint4*>(ws + PROB_OFF);
    float ls = 0.0f;
    unsigned lc = 0;
    for (int it = 0; it < ITERS; ++it) {
        int q = it * (NBLK * 256) + blockIdx.x * 256 + threadIdx.x;
        int pix0 = q * 4;
        uint4 v = pbv[q];
        int4 t4 = *reinterpret_cast<const int4*>(target + pix0);
        unsigned a[4] = {v.x, v.y, v.z, v.w};
        int tt[4] = {t4.x, t4.y, t4.z, t4.w};
#pragma unroll
        for (int p = 0; p < 4; ++p) {
            bool valid = (tt[p] != IGNORE_LBL);
            float pr = __uint_as_float(a[p]);
            if (valid && pr <= thr) { ls += -logf(fmaxf(pr, 1e-37f)); lc += 1u; }
        }
    }
    for (int off = 32; off; off >>= 1) {
        ls += __shfl_down(ls, off);
        lc += __shfl_down(lc, off);
    }
    __shared__ float wsum[4];
    __shared__ unsigned wcnt[4];
    if ((threadIdx.x & 63) == 0) { wsum[threadIdx.x >> 6] = ls; wcnt[threadIdx.x >> 6] = lc; }
    __syncthreads();
    if (threadIdx.x == 0) {
        atomicAdd(reinterpret_cast<double*>(ws + W_SLOW_SUM),
                  (double)(wsum[0] + wsum[1] + wsum[2] + wsum[3]));
        atomicAdd(ws + W_SLOW_CNT, wcnt[0] + wcnt[1] + wcnt[2] + wcnt[3]);
    }
}

__global__ void k_finalize(const unsigned* __restrict__ ws, float* __restrict__ out) {
    if (threadIdx.x == 0 && blockIdx.x == 0) {
        unsigned tot_cnt = ws[W_TOT_CNT];
        bool do_ohem = (tot_cnt > 0u) && (tot_cnt >= (unsigned)KSEL);
        double s; unsigned c;
        if (!do_ohem) {
            s = *reinterpret_cast<const double*>(ws + W_TOT_SUM);  c = tot_cnt;
        } else if (ws[W_EARLY]) {
            s = *reinterpret_cast<const double*>(ws + W_SPEC_SUM); c = ws[W_SPEC_CNT];
        } else {
            s = *reinterpret_cast<const double*>(ws + W_SLOW_SUM); c = ws[W_SLOW_CNT];
        }
        out[0] = (float)(s / (double)((c > 0u) ? c : 1u));
    }
}

extern "C" void kernel_launch(void* const* d_in, const int* in_sizes, int n_in,
                              void* d_out, int out_size, void* d_ws, size_t ws_size,
                              hipStream_t stream) {
    const float* pred = (const float*)d_in[0];
    const int* target = (const int*)d_in[1];
    unsigned* ws = (unsigned*)d_ws;
    float* out = (float*)d_out;

    // Try the fused cooperative kernel; deterministic decision each call.
    int occ = 0;
    hipError_t qe = hipOccupancyMaxActiveBlocksPerMultiprocessor(
        &occ, reinterpret_cast<const void*>(k_fused), 256, 0);
    if (qe == hipSuccess && occ >= 1) {
        int grid = occ * 256;                 // 256 CUs on MI355X
        if (grid > 2048) grid = 2048;
        void* args[] = {(void*)&pred, (void*)&target, (void*)&ws, (void*)&out};
        hipError_t le = hipLaunchCooperativeKernel(
            reinterpret_cast<const void*>(k_fused), dim3(grid), dim3(256),
            args, 0, stream);
        if (le == hipSuccess) return;
    }

    // Fallback: proven 6-dispatch pipeline.
    k_init<<<1, 256, 0, stream>>>(ws);
    k_pass1<<<NBLK, 256, 0, stream>>>(pred, target, ws);
    k_refine<2><<<NBLK, 256, 0, stream>>>(ws);
    k_refine<3><<<NBLK, 256, 0, stream>>>(ws);
    k_final<<<NBLK, 256, 0, stream>>>(ws, target);
    k_finalize<<<1, 64, 0, stream>>>(ws, out);
}